// Round 1
// baseline (16603.682 us; speedup 1.0000x reference)
//
#include <hip/hip_runtime.h>
#include <hip/hip_bf16.h>

#define B_TOT 1024
#define T_STEPS 128
#define N_NODES 5
#define FML 32
#define IN_F 165     // 5 + 160
#define F1 256
#define F2 256
#define F3 512
#define NCLS 7
#define BM 8         // batch rows per block in recurrence

// ---------------- Kernel 1: persistent recurrence ----------------
// 128 blocks x 256 threads; block b owns rows [b*8, b*8+8).
// State + x_t live in LDS as "inp" [8][168] (cols 0..4 = x_t, 5+i*32+c = state[i][c]).
__global__ __launch_bounds__(256) void recur_kernel(
    const float* __restrict__ x,
    const float* __restrict__ Wf1, const float* __restrict__ bf1,
    const float* __restrict__ Wf2, const float* __restrict__ bf2,
    const float* __restrict__ Wf3, const float* __restrict__ bf3,
    float* __restrict__ feat_out) {
  __shared__ __align__(16) float inp[BM][168];   // 165 used, pad to 168 (16B aligned rows)
  __shared__ __align__(16) float h1[BM][F1];
  __shared__ __align__(16) float h2[BM][F2];

  const int tid = threadIdx.x;
  const int r0 = blockIdx.x * BM;

  // zero state (and pad)
  for (int idx = tid; idx < BM * 168; idx += 256) ((float*)inp)[idx] = 0.f;
  __syncthreads();

  for (int t = 0; t < T_STEPS; ++t) {
    // load x_t: x[b][n][t], layout b*640 + n*128 + t
    if (tid < BM * N_NODES) {
      int r = tid / N_NODES, n = tid % N_NODES;
      inp[r][n] = x[(size_t)(r0 + r) * (N_NODES * T_STEPS) + n * T_STEPS + t];
    }
    __syncthreads();

    for (int i = 0; i < N_NODES; ++i) {
      // ---- layer 1: [8 x 165] @ [165 x 256] -> h1, col = tid ----
      {
        const float* W = Wf1 + (size_t)i * IN_F * F1;
        float acc[BM];
#pragma unroll
        for (int r = 0; r < BM; ++r) acc[r] = 0.f;
        int k = 0;
        for (; k + 3 < IN_F; k += 4) {
          float w0 = W[(k + 0) * F1 + tid];
          float w1 = W[(k + 1) * F1 + tid];
          float w2 = W[(k + 2) * F1 + tid];
          float w3 = W[(k + 3) * F1 + tid];
#pragma unroll
          for (int r = 0; r < BM; ++r) {
            float4 v = *reinterpret_cast<const float4*>(&inp[r][k]);
            acc[r] = fmaf(v.x, w0, acc[r]);
            acc[r] = fmaf(v.y, w1, acc[r]);
            acc[r] = fmaf(v.z, w2, acc[r]);
            acc[r] = fmaf(v.w, w3, acc[r]);
          }
        }
        { // tail k = 164
          float w0 = W[164 * F1 + tid];
#pragma unroll
          for (int r = 0; r < BM; ++r) acc[r] = fmaf(inp[r][164], w0, acc[r]);
        }
        float b = bf1[i * F1 + tid];
#pragma unroll
        for (int r = 0; r < BM; ++r) h1[r][tid] = fmaxf(acc[r] + b, 0.f);
      }
      __syncthreads();

      // ---- layer 2: [8 x 256] @ [256 x 256] -> h2, col = tid ----
      {
        const float* W = Wf2 + (size_t)i * F1 * F2;
        float acc[BM];
#pragma unroll
        for (int r = 0; r < BM; ++r) acc[r] = 0.f;
        for (int k = 0; k < F1; k += 4) {
          float w0 = W[(k + 0) * F2 + tid];
          float w1 = W[(k + 1) * F2 + tid];
          float w2 = W[(k + 2) * F2 + tid];
          float w3 = W[(k + 3) * F2 + tid];
#pragma unroll
          for (int r = 0; r < BM; ++r) {
            float4 v = *reinterpret_cast<const float4*>(&h1[r][k]);
            acc[r] = fmaf(v.x, w0, acc[r]);
            acc[r] = fmaf(v.y, w1, acc[r]);
            acc[r] = fmaf(v.z, w2, acc[r]);
            acc[r] = fmaf(v.w, w3, acc[r]);
          }
        }
        float b = bf2[i * F2 + tid];
#pragma unroll
        for (int r = 0; r < BM; ++r) h2[r][tid] = fmaxf(acc[r] + b, 0.f);
      }
      __syncthreads();

      // ---- layer 3: [8 x 256] @ [256 x 32] -> state slice i ----
      {
        const float* W = Wf3 + (size_t)i * F2 * FML;
        int r = tid >> 5, c = tid & 31;
        float acc = 0.f;
        for (int k = 0; k < F2; k += 4) {
          float4 v = *reinterpret_cast<const float4*>(&h2[r][k]);
          acc = fmaf(v.x, W[(k + 0) * FML + c], acc);
          acc = fmaf(v.y, W[(k + 1) * FML + c], acc);
          acc = fmaf(v.z, W[(k + 2) * FML + c], acc);
          acc = fmaf(v.w, W[(k + 3) * FML + c], acc);
        }
        float s = fmaxf(acc + bf3[i * FML + c], 0.f);
        inp[r][5 + i * FML + c] = s;   // Gauss-Seidel: visible to node i+1 after barrier
      }
      __syncthreads();
    }
  }

  // feat = [x_{T-1} | state] = inp[r][0..164]
  for (int idx = tid; idx < BM * IN_F; idx += 256) {
    int r = idx / IN_F, c = idx % IN_F;
    feat_out[(size_t)(r0 + r) * IN_F + c] = inp[r][c];
  }
}

// ---------------- Kernel 2: head layer 1 (feat @ Wo1 + bo1, ReLU) ----------------
__global__ __launch_bounds__(256) void head1_kernel(
    const float* __restrict__ feat, const float* __restrict__ Wo1,
    const float* __restrict__ bo1, float* __restrict__ H) {
  __shared__ __align__(16) float f[BM][168];
  const int tid = threadIdx.x;
  const int r0 = blockIdx.x * BM;
  for (int idx = tid; idx < BM * 168; idx += 256) {
    int r = idx / 168, c = idx % 168;
    f[r][c] = (c < IN_F) ? feat[(size_t)(r0 + r) * IN_F + c] : 0.f;
  }
  __syncthreads();
  const int c0 = tid, c1 = tid + 256;
  float acc0[BM], acc1[BM];
#pragma unroll
  for (int r = 0; r < BM; ++r) { acc0[r] = 0.f; acc1[r] = 0.f; }
  int k = 0;
  for (; k + 3 < IN_F; k += 4) {
    float w00 = Wo1[(k + 0) * F3 + c0], w01 = Wo1[(k + 0) * F3 + c1];
    float w10 = Wo1[(k + 1) * F3 + c0], w11 = Wo1[(k + 1) * F3 + c1];
    float w20 = Wo1[(k + 2) * F3 + c0], w21 = Wo1[(k + 2) * F3 + c1];
    float w30 = Wo1[(k + 3) * F3 + c0], w31 = Wo1[(k + 3) * F3 + c1];
#pragma unroll
    for (int r = 0; r < BM; ++r) {
      float4 v = *reinterpret_cast<const float4*>(&f[r][k]);
      acc0[r] = fmaf(v.x, w00, acc0[r]); acc1[r] = fmaf(v.x, w01, acc1[r]);
      acc0[r] = fmaf(v.y, w10, acc0[r]); acc1[r] = fmaf(v.y, w11, acc1[r]);
      acc0[r] = fmaf(v.z, w20, acc0[r]); acc1[r] = fmaf(v.z, w21, acc1[r]);
      acc0[r] = fmaf(v.w, w30, acc0[r]); acc1[r] = fmaf(v.w, w31, acc1[r]);
    }
  }
  { // tail k = 164
    float w0 = Wo1[164 * F3 + c0], w1 = Wo1[164 * F3 + c1];
#pragma unroll
    for (int r = 0; r < BM; ++r) {
      acc0[r] = fmaf(f[r][164], w0, acc0[r]);
      acc1[r] = fmaf(f[r][164], w1, acc1[r]);
    }
  }
  float b0 = bo1[c0], b1 = bo1[c1];
#pragma unroll
  for (int r = 0; r < BM; ++r) {
    H[(size_t)(r0 + r) * F3 + c0] = fmaxf(acc0[r] + b0, 0.f);
    H[(size_t)(r0 + r) * F3 + c1] = fmaxf(acc1[r] + b1, 0.f);
  }
}

// ---------------- Kernel 3: BN stats -> per-column scale/shift ----------------
__global__ __launch_bounds__(256) void bn_stats_kernel(
    const float* __restrict__ H, const float* __restrict__ gamma,
    const float* __restrict__ beta, float* __restrict__ ab) {
  const int c = blockIdx.x;      // 512 columns
  const int tid = threadIdx.x;
  float s = 0.f, q = 0.f;
  for (int r = tid; r < B_TOT; r += 256) {
    float v = H[(size_t)r * F3 + c];
    s += v; q += v * v;
  }
  __shared__ float ls[256], lq[256];
  ls[tid] = s; lq[tid] = q;
  __syncthreads();
  for (int off = 128; off; off >>= 1) {
    if (tid < off) { ls[tid] += ls[tid + off]; lq[tid] += lq[tid + off]; }
    __syncthreads();
  }
  if (tid == 0) {
    float mu = ls[0] * (1.f / B_TOT);
    float var = lq[0] * (1.f / B_TOT) - mu * mu;  // biased variance
    float inv = rsqrtf(var + 1e-5f);
    float a = gamma[c] * inv;
    ab[c] = a;
    ab[F3 + c] = beta[c] - mu * a;
  }
}

// ---------------- Kernel 4: logits + softmax (1 wave per row) ----------------
__global__ __launch_bounds__(256) void out_kernel(
    const float* __restrict__ H, const float* __restrict__ ab,
    const float* __restrict__ Wo2, const float* __restrict__ bo2,
    float* __restrict__ out) {
  const int wid = threadIdx.x >> 6, lane = threadIdx.x & 63;
  const int r = blockIdx.x * 4 + wid;
  float acc[NCLS];
#pragma unroll
  for (int j = 0; j < NCLS; ++j) acc[j] = 0.f;
  for (int k = lane; k < F3; k += 64) {
    float hv = H[(size_t)r * F3 + k] * ab[k] + ab[F3 + k];
#pragma unroll
    for (int j = 0; j < NCLS; ++j) acc[j] = fmaf(hv, Wo2[k * NCLS + j], acc[j]);
  }
#pragma unroll
  for (int j = 0; j < NCLS; ++j)
    for (int off = 32; off; off >>= 1) acc[j] += __shfl_xor(acc[j], off);
  if (lane == 0) {
    float lg[NCLS], mx = -1e30f;
#pragma unroll
    for (int j = 0; j < NCLS; ++j) { lg[j] = acc[j] + bo2[j]; mx = fmaxf(mx, lg[j]); }
    float sum = 0.f;
#pragma unroll
    for (int j = 0; j < NCLS; ++j) { lg[j] = __expf(lg[j] - mx); sum += lg[j]; }
    float inv = 1.f / sum;
#pragma unroll
    for (int j = 0; j < NCLS; ++j) out[(size_t)r * NCLS + j] = lg[j] * inv;
  }
}

extern "C" void kernel_launch(void* const* d_in, const int* in_sizes, int n_in,
                              void* d_out, int out_size, void* d_ws, size_t ws_size,
                              hipStream_t stream) {
  const float* x   = (const float*)d_in[0];
  const float* Wf1 = (const float*)d_in[1];
  const float* bf1 = (const float*)d_in[2];
  const float* Wf2 = (const float*)d_in[3];
  const float* bf2 = (const float*)d_in[4];
  const float* Wf3 = (const float*)d_in[5];
  const float* bf3 = (const float*)d_in[6];
  const float* Wo1 = (const float*)d_in[7];
  const float* bo1 = (const float*)d_in[8];
  const float* gamma = (const float*)d_in[9];
  const float* beta  = (const float*)d_in[10];
  const float* Wo2 = (const float*)d_in[11];
  const float* bo2 = (const float*)d_in[12];
  float* out = (float*)d_out;

  char* ws = (char*)d_ws;
  float* feat = (float*)ws;                        // 1024*165*4  = 675,840 B
  float* H    = (float*)(ws + 675840);             // 1024*512*4  = 2,097,152 B
  float* ab   = (float*)(ws + 675840 + 2097152);   // 2*512*4     = 4,096 B

  recur_kernel<<<B_TOT / BM, 256, 0, stream>>>(x, Wf1, bf1, Wf2, bf2, Wf3, bf3, feat);
  head1_kernel<<<B_TOT / BM, 256, 0, stream>>>(feat, Wo1, bo1, H);
  bn_stats_kernel<<<F3, 256, 0, stream>>>(H, gamma, beta, ab);
  out_kernel<<<B_TOT / 4, 256, 0, stream>>>(H, ab, Wo2, bo2, out);
}

// Round 2
// 1680.293 us; speedup vs baseline: 9.8814x; 9.8814x over previous
//
#include <hip/hip_runtime.h>
#include <hip/hip_bf16.h>

#define B_TOT 1024
#define T_STEPS 128
#define N_NODES 5
#define FML 32
#define IN_F 165     // 5 + 160
#define F1 256
#define F2 256
#define F3 512
#define NCLS 7
#define BM 16        // batch rows per block in recurrence (MFMA M)
#define BMH 8        // rows per block in head kernel

typedef __attribute__((ext_vector_type(8))) short bfrag;   // 8 bf16 (4 VGPRs)
typedef __attribute__((ext_vector_type(4))) float f32x4;

// Packed fragment counts per node
#define L1_KT 6      // K padded 165 -> 192
#define L1_CT 16
#define L2_KT 8
#define L2_CT 16
#define L3_KT 8
#define L3_CT 2
#define L1_FRAGS (L1_KT * L1_CT)   // 96
#define L2_FRAGS (L2_KT * L2_CT)   // 128
#define L3_FRAGS (L3_KT * L3_CT)   // 16

__device__ __forceinline__ __hip_bfloat16 tobf(float v) { return __float2bfloat16(v); }

// ---------------- Kernel 0: pack weights into MFMA-fragment layout (bf16) ----------------
// frag layout: [node][kt*CT+ct][lane][8 elems]; elem (lane,e) = W[kt*32+(lane>>4)*8+e][ct*16+(lane&15)]
__global__ __launch_bounds__(256) void pack_weights(
    const float* __restrict__ Wf1, const float* __restrict__ Wf2, const float* __restrict__ Wf3,
    __hip_bfloat16* __restrict__ p1, __hip_bfloat16* __restrict__ p2, __hip_bfloat16* __restrict__ p3) {
  int tid = blockIdx.x * 256 + threadIdx.x;   // total 5*240*64 = 76800
  int node = tid / (240 * 64);
  int rem  = tid % (240 * 64);
  int frag = rem >> 6;
  int lane = rem & 63;
  int g = lane >> 4, c16 = lane & 15;
  if (frag < L1_FRAGS) {
    int kt = frag / L1_CT, ct = frag % L1_CT;
    __hip_bfloat16* dst = p1 + (((size_t)node * L1_FRAGS + frag) * 64 + lane) * 8;
    const float* W = Wf1 + (size_t)node * IN_F * F1;
#pragma unroll
    for (int e = 0; e < 8; ++e) {
      int k = kt * 32 + g * 8 + e;
      float v = (k < IN_F) ? W[(size_t)k * F1 + ct * 16 + c16] : 0.f;
      dst[e] = tobf(v);
    }
  } else if (frag < L1_FRAGS + L2_FRAGS) {
    int f = frag - L1_FRAGS;
    __hip_bfloat16* dst = p2 + (((size_t)node * L2_FRAGS + f) * 64 + lane) * 8;
    const float* W = Wf2 + (size_t)node * F1 * F2;
    int kt = f / L2_CT, ct = f % L2_CT;
#pragma unroll
    for (int e = 0; e < 8; ++e) {
      int k = kt * 32 + g * 8 + e;
      dst[e] = tobf(W[(size_t)k * F2 + ct * 16 + c16]);
    }
  } else {
    int f = frag - L1_FRAGS - L2_FRAGS;
    __hip_bfloat16* dst = p3 + (((size_t)node * L3_FRAGS + f) * 64 + lane) * 8;
    const float* W = Wf3 + (size_t)node * F2 * FML;
    int kt = f / L3_CT, ct = f % L3_CT;
#pragma unroll
    for (int e = 0; e < 8; ++e) {
      int k = kt * 32 + g * 8 + e;
      dst[e] = tobf(W[(size_t)k * FML + ct * 16 + c16]);
    }
  }
}

// ---------------- Kernel 1: persistent recurrence with MFMA ----------------
// 64 blocks x 512 threads (8 waves). Block owns rows [b*16, b*16+16).
// inp: [16][200] bf16 (cols 0..4 x_t, 5..164 state, 165..191 zero pad, 192..199 stride pad)
#define INP_STRIDE 200
#define H_STRIDE 264
__global__ __launch_bounds__(512) void recur_kernel(
    const float* __restrict__ x,
    const __hip_bfloat16* __restrict__ p1, const float* __restrict__ bf1,
    const __hip_bfloat16* __restrict__ p2, const float* __restrict__ bf2,
    const __hip_bfloat16* __restrict__ p3, const float* __restrict__ bf3,
    float* __restrict__ feat_out) {
  __shared__ __align__(16) __hip_bfloat16 inp_s[BM][INP_STRIDE];
  __shared__ __align__(16) __hip_bfloat16 h1_s[BM][H_STRIDE];
  __shared__ __align__(16) __hip_bfloat16 h2_s[BM][H_STRIDE];

  const int tid = threadIdx.x;
  const int lane = tid & 63;
  const int w = tid >> 6;          // wave 0..7
  const int g = lane >> 4;         // k-group / row-group
  const int c16 = lane & 15;       // col-within-tile / A-row
  const int r0 = blockIdx.x * BM;

  // zero inp (incl. k-pad)
  for (int idx = tid; idx < BM * INP_STRIDE; idx += 512)
    ((__hip_bfloat16*)inp_s)[idx] = tobf(0.f);
  __syncthreads();

  for (int t = 0; t < T_STEPS; ++t) {
    // x_t -> inp cols 0..4 (bf16)
    if (tid < BM * N_NODES) {
      int r = tid / N_NODES, n = tid % N_NODES;
      inp_s[r][n] = tobf(x[(size_t)(r0 + r) * (N_NODES * T_STEPS) + n * T_STEPS + t]);
    }
    __syncthreads();

    for (int i = 0; i < N_NODES; ++i) {
      // ---------- layer 1: [16x192] @ [192x256] ----------
      {
        const int ct0 = 2 * w, ct1 = 2 * w + 1;
        const bfrag* P = (const bfrag*)p1 + (size_t)i * L1_FRAGS * 64;
        bfrag b0[L1_KT], b1[L1_KT], a[L1_KT];
#pragma unroll
        for (int kt = 0; kt < L1_KT; ++kt) {
          b0[kt] = P[(kt * L1_CT + ct0) * 64 + lane];
          b1[kt] = P[(kt * L1_CT + ct1) * 64 + lane];
        }
#pragma unroll
        for (int kt = 0; kt < L1_KT; ++kt)
          a[kt] = *(const bfrag*)&inp_s[c16][kt * 32 + g * 8];
        f32x4 acc0 = {0.f, 0.f, 0.f, 0.f}, acc1 = {0.f, 0.f, 0.f, 0.f};
#pragma unroll
        for (int kt = 0; kt < L1_KT; ++kt) {
          acc0 = __builtin_amdgcn_mfma_f32_16x16x32_bf16(a[kt], b0[kt], acc0, 0, 0, 0);
          acc1 = __builtin_amdgcn_mfma_f32_16x16x32_bf16(a[kt], b1[kt], acc1, 0, 0, 0);
        }
        float bia0 = bf1[i * F1 + ct0 * 16 + c16];
        float bia1 = bf1[i * F1 + ct1 * 16 + c16];
#pragma unroll
        for (int e = 0; e < 4; ++e) {
          h1_s[g * 4 + e][ct0 * 16 + c16] = tobf(fmaxf(acc0[e] + bia0, 0.f));
          h1_s[g * 4 + e][ct1 * 16 + c16] = tobf(fmaxf(acc1[e] + bia1, 0.f));
        }
      }
      __syncthreads();

      // ---------- layer 2: [16x256] @ [256x256] ----------
      {
        const int ct0 = 2 * w, ct1 = 2 * w + 1;
        const bfrag* P = (const bfrag*)p2 + (size_t)i * L2_FRAGS * 64;
        bfrag b0[L2_KT], b1[L2_KT], a[L2_KT];
#pragma unroll
        for (int kt = 0; kt < L2_KT; ++kt) {
          b0[kt] = P[(kt * L2_CT + ct0) * 64 + lane];
          b1[kt] = P[(kt * L2_CT + ct1) * 64 + lane];
        }
#pragma unroll
        for (int kt = 0; kt < L2_KT; ++kt)
          a[kt] = *(const bfrag*)&h1_s[c16][kt * 32 + g * 8];
        f32x4 acc0 = {0.f, 0.f, 0.f, 0.f}, acc1 = {0.f, 0.f, 0.f, 0.f};
#pragma unroll
        for (int kt = 0; kt < L2_KT; ++kt) {
          acc0 = __builtin_amdgcn_mfma_f32_16x16x32_bf16(a[kt], b0[kt], acc0, 0, 0, 0);
          acc1 = __builtin_amdgcn_mfma_f32_16x16x32_bf16(a[kt], b1[kt], acc1, 0, 0, 0);
        }
        float bia0 = bf2[i * F2 + ct0 * 16 + c16];
        float bia1 = bf2[i * F2 + ct1 * 16 + c16];
#pragma unroll
        for (int e = 0; e < 4; ++e) {
          h2_s[g * 4 + e][ct0 * 16 + c16] = tobf(fmaxf(acc0[e] + bia0, 0.f));
          h2_s[g * 4 + e][ct1 * 16 + c16] = tobf(fmaxf(acc1[e] + bia1, 0.f));
        }
      }
      __syncthreads();

      // ---------- layer 3: [16x256] @ [256x32] -> state slice i ----------
      if (w < 2) {
        const int ct = w;
        const bfrag* P = (const bfrag*)p3 + (size_t)i * L3_FRAGS * 64;
        bfrag b[L3_KT], a[L3_KT];
#pragma unroll
        for (int kt = 0; kt < L3_KT; ++kt)
          b[kt] = P[(kt * L3_CT + ct) * 64 + lane];
#pragma unroll
        for (int kt = 0; kt < L3_KT; ++kt)
          a[kt] = *(const bfrag*)&h2_s[c16][kt * 32 + g * 8];
        f32x4 acc = {0.f, 0.f, 0.f, 0.f};
#pragma unroll
        for (int kt = 0; kt < L3_KT; ++kt)
          acc = __builtin_amdgcn_mfma_f32_16x16x32_bf16(a[kt], b[kt], acc, 0, 0, 0);
        float bia = bf3[i * FML + ct * 16 + c16];
        int sc = i * FML + ct * 16 + c16;   // state col 0..159
#pragma unroll
        for (int e = 0; e < 4; ++e) {
          float v = fmaxf(acc[e] + bia, 0.f);
          int row = g * 4 + e;
          inp_s[row][5 + sc] = tobf(v);
          if (t == T_STEPS - 1)
            feat_out[(size_t)(r0 + row) * IN_F + 5 + sc] = v;   // fp32 state for head
        }
      }
      __syncthreads();
    }
  }

  // feat x-part (fp32, exact)
  if (tid < BM * N_NODES) {
    int r = tid / N_NODES, n = tid % N_NODES;
    feat_out[(size_t)(r0 + r) * IN_F + n] =
        x[(size_t)(r0 + r) * (N_NODES * T_STEPS) + n * T_STEPS + (T_STEPS - 1)];
  }
}

// ---------------- Kernel 2: head layer 1 (feat @ Wo1 + bo1, ReLU) ----------------
__global__ __launch_bounds__(256) void head1_kernel(
    const float* __restrict__ feat, const float* __restrict__ Wo1,
    const float* __restrict__ bo1, float* __restrict__ H) {
  __shared__ __align__(16) float f[BMH][168];
  const int tid = threadIdx.x;
  const int r0 = blockIdx.x * BMH;
  for (int idx = tid; idx < BMH * 168; idx += 256) {
    int r = idx / 168, c = idx % 168;
    f[r][c] = (c < IN_F) ? feat[(size_t)(r0 + r) * IN_F + c] : 0.f;
  }
  __syncthreads();
  const int c0 = tid, c1 = tid + 256;
  float acc0[BMH], acc1[BMH];
#pragma unroll
  for (int r = 0; r < BMH; ++r) { acc0[r] = 0.f; acc1[r] = 0.f; }
  int k = 0;
  for (; k + 3 < IN_F; k += 4) {
    float w00 = Wo1[(k + 0) * F3 + c0], w01 = Wo1[(k + 0) * F3 + c1];
    float w10 = Wo1[(k + 1) * F3 + c0], w11 = Wo1[(k + 1) * F3 + c1];
    float w20 = Wo1[(k + 2) * F3 + c0], w21 = Wo1[(k + 2) * F3 + c1];
    float w30 = Wo1[(k + 3) * F3 + c0], w31 = Wo1[(k + 3) * F3 + c1];
#pragma unroll
    for (int r = 0; r < BMH; ++r) {
      float4 v = *reinterpret_cast<const float4*>(&f[r][k]);
      acc0[r] = fmaf(v.x, w00, acc0[r]); acc1[r] = fmaf(v.x, w01, acc1[r]);
      acc0[r] = fmaf(v.y, w10, acc0[r]); acc1[r] = fmaf(v.y, w11, acc1[r]);
      acc0[r] = fmaf(v.z, w20, acc0[r]); acc1[r] = fmaf(v.z, w21, acc1[r]);
      acc0[r] = fmaf(v.w, w30, acc0[r]); acc1[r] = fmaf(v.w, w31, acc1[r]);
    }
  }
  {
    float w0 = Wo1[164 * F3 + c0], w1 = Wo1[164 * F3 + c1];
#pragma unroll
    for (int r = 0; r < BMH; ++r) {
      acc0[r] = fmaf(f[r][164], w0, acc0[r]);
      acc1[r] = fmaf(f[r][164], w1, acc1[r]);
    }
  }
  float b0 = bo1[c0], b1 = bo1[c1];
#pragma unroll
  for (int r = 0; r < BMH; ++r) {
    H[(size_t)(r0 + r) * F3 + c0] = fmaxf(acc0[r] + b0, 0.f);
    H[(size_t)(r0 + r) * F3 + c1] = fmaxf(acc1[r] + b1, 0.f);
  }
}

// ---------------- Kernel 3: BN stats -> per-column scale/shift ----------------
__global__ __launch_bounds__(256) void bn_stats_kernel(
    const float* __restrict__ H, const float* __restrict__ gamma,
    const float* __restrict__ beta, float* __restrict__ ab) {
  const int c = blockIdx.x;
  const int tid = threadIdx.x;
  float s = 0.f, q = 0.f;
  for (int r = tid; r < B_TOT; r += 256) {
    float v = H[(size_t)r * F3 + c];
    s += v; q += v * v;
  }
  __shared__ float ls[256], lq[256];
  ls[tid] = s; lq[tid] = q;
  __syncthreads();
  for (int off = 128; off; off >>= 1) {
    if (tid < off) { ls[tid] += ls[tid + off]; lq[tid] += lq[tid + off]; }
    __syncthreads();
  }
  if (tid == 0) {
    float mu = ls[0] * (1.f / B_TOT);
    float var = lq[0] * (1.f / B_TOT) - mu * mu;
    float inv = rsqrtf(var + 1e-5f);
    float a = gamma[c] * inv;
    ab[c] = a;
    ab[F3 + c] = beta[c] - mu * a;
  }
}

// ---------------- Kernel 4: logits + softmax (1 wave per row) ----------------
__global__ __launch_bounds__(256) void out_kernel(
    const float* __restrict__ H, const float* __restrict__ ab,
    const float* __restrict__ Wo2, const float* __restrict__ bo2,
    float* __restrict__ out) {
  const int wid = threadIdx.x >> 6, lane = threadIdx.x & 63;
  const int r = blockIdx.x * 4 + wid;
  float acc[NCLS];
#pragma unroll
  for (int j = 0; j < NCLS; ++j) acc[j] = 0.f;
  for (int k = lane; k < F3; k += 64) {
    float hv = H[(size_t)r * F3 + k] * ab[k] + ab[F3 + k];
#pragma unroll
    for (int j = 0; j < NCLS; ++j) acc[j] = fmaf(hv, Wo2[k * NCLS + j], acc[j]);
  }
#pragma unroll
  for (int j = 0; j < NCLS; ++j)
    for (int off = 32; off; off >>= 1) acc[j] += __shfl_xor(acc[j], off);
  if (lane == 0) {
    float lg[NCLS], mx = -1e30f;
#pragma unroll
    for (int j = 0; j < NCLS; ++j) { lg[j] = acc[j] + bo2[j]; mx = fmaxf(mx, lg[j]); }
    float sum = 0.f;
#pragma unroll
    for (int j = 0; j < NCLS; ++j) { lg[j] = __expf(lg[j] - mx); sum += lg[j]; }
    float inv = 1.f / sum;
#pragma unroll
    for (int j = 0; j < NCLS; ++j) out[(size_t)r * NCLS + j] = lg[j] * inv;
  }
}

extern "C" void kernel_launch(void* const* d_in, const int* in_sizes, int n_in,
                              void* d_out, int out_size, void* d_ws, size_t ws_size,
                              hipStream_t stream) {
  const float* x   = (const float*)d_in[0];
  const float* Wf1 = (const float*)d_in[1];
  const float* bf1 = (const float*)d_in[2];
  const float* Wf2 = (const float*)d_in[3];
  const float* bf2 = (const float*)d_in[4];
  const float* Wf3 = (const float*)d_in[5];
  const float* bf3 = (const float*)d_in[6];
  const float* Wo1 = (const float*)d_in[7];
  const float* bo1 = (const float*)d_in[8];
  const float* gamma = (const float*)d_in[9];
  const float* beta  = (const float*)d_in[10];
  const float* Wo2 = (const float*)d_in[11];
  const float* bo2 = (const float*)d_in[12];
  float* out = (float*)d_out;

  char* ws = (char*)d_ws;
  size_t off = 0;
  __hip_bfloat16* p1 = (__hip_bfloat16*)(ws + off); off += (size_t)N_NODES * L1_FRAGS * 64 * 8 * 2; // 491520
  __hip_bfloat16* p2 = (__hip_bfloat16*)(ws + off); off += (size_t)N_NODES * L2_FRAGS * 64 * 8 * 2; // 655360
  __hip_bfloat16* p3 = (__hip_bfloat16*)(ws + off); off += (size_t)N_NODES * L3_FRAGS * 64 * 8 * 2; // 81920
  float* feat = (float*)(ws + off); off += (size_t)B_TOT * IN_F * 4;                                 // 675840
  float* H    = (float*)(ws + off); off += (size_t)B_TOT * F3 * 4;                                   // 2097152
  float* ab   = (float*)(ws + off); off += 2 * F3 * 4;

  pack_weights<<<300, 256, 0, stream>>>(Wf1, Wf2, Wf3, p1, p2, p3);
  recur_kernel<<<B_TOT / BM, 512, 0, stream>>>(x, p1, bf1, p2, bf2, p3, bf3, feat);
  head1_kernel<<<B_TOT / BMH, 256, 0, stream>>>(feat, Wo1, bo1, H);
  bn_stats_kernel<<<F3, 256, 0, stream>>>(H, gamma, beta, ab);
  out_kernel<<<B_TOT / 4, 256, 0, stream>>>(H, ab, Wo2, bo2, out);
}